// Round 6
// baseline (14975.880 us; speedup 1.0000x reference)
//
#include <hip/hip_runtime.h>

// LSTM: B=256, T=512, I=64, H=512, G=4H=2048.
// gates = W @ [h; x], W = [R | kernel^T], K = 576.
// Persistent: 32 WGs x 1024 thr = 16 groups x 2 WGs. Each WG owns 1024
// gate-rows (= 256 h cols) of its group's 16 batches; W slice register-
// resident (288 VGPR/lane). Own h half stays in LDS; only the peer half
// crosses the fabric as TAGGED u64s ((s<<16|bf16) pairs) with relaxed
// agent-scope atomics -> fan-in 1, poll IS the data load.
#define TSTEPS 512
#define BATCH  256
#define ISZ    64
#define HSZ    512
#define GSZ    2048
#define NKT    18
#define BG     16

typedef __attribute__((ext_vector_type(8))) short short8;
typedef __attribute__((ext_vector_type(4))) float f32x4;
typedef __attribute__((ext_vector_type(4))) unsigned int u32x4;
typedef unsigned long long u64t;

static __device__ __forceinline__ unsigned short f2bf(float f) {
    unsigned int u = __float_as_uint(f);
    return (unsigned short)((u + 0x7fffu + ((u >> 16) & 1u)) >> 16);  // RNE
}
static __device__ __forceinline__ float sig_(float x) {
    return 1.0f / (1.0f + __expf(-x));
}
static __device__ __forceinline__ float tanh_(float x) {
    float e = __expf(-2.0f * fabsf(x));
    float t = (1.0f - e) / (1.0f + e);
    return copysignf(t, x);
}
static __device__ __forceinline__ u64t ld_tag(const u64t* p) {
    return __hip_atomic_load(p, __ATOMIC_RELAXED, __HIP_MEMORY_SCOPE_AGENT);
}
static __device__ __forceinline__ void st_tag(u64t* p, u64t v) {
    __hip_atomic_store(p, v, __ATOMIC_RELAXED, __HIP_MEMORY_SCOPE_AGENT);
}

// Pack W = [R | kernel^T] (fp32) into bf16 MFMA A-fragment order.
// Frag t = ((jj*8 + m)*18 + kt)*64 + lane; row r = 16m + (lane&15);
// gate q = r&3; hco = r>>2; global row = q*512 + jj*32 + hco.
__global__ void pack_w(const float* __restrict__ R, const float* __restrict__ Kin,
                       unsigned short* __restrict__ wpack)
{
    const int t  = blockIdx.x * 256 + threadIdx.x;
    const int l  = t & 63;
    const int kt = (t >> 6) % NKT;
    const int m  = (t / (64 * NKT)) & 7;
    const int jj = t / (64 * NKT * 8);
    const int r   = 16 * m + (l & 15);
    const int q   = r & 3;
    const int hco = r >> 2;
    const int grow  = q * HSZ + jj * 32 + hco;
    const int kbase = kt * 32 + (l >> 4) * 8;
    unsigned int pk[4];
#pragma unroll
    for (int p = 0; p < 4; ++p) {
        const int k0 = kbase + 2 * p;
        const int k1 = k0 + 1;
        const float f0 = (k0 < HSZ) ? R[(size_t)grow * HSZ + k0]
                                    : Kin[(size_t)(k0 - HSZ) * GSZ + grow];
        const float f1 = (k1 < HSZ) ? R[(size_t)grow * HSZ + k1]
                                    : Kin[(size_t)(k1 - HSZ) * GSZ + grow];
        pk[p] = (unsigned)f2bf(f0) | ((unsigned)f2bf(f1) << 16);
    }
    uint4 v = make_uint4(pk[0], pk[1], pk[2], pk[3]);
    *reinterpret_cast<uint4*>(wpack + (size_t)t * 8) = v;
}

// Zero tagged h buffer each launch (tag 0 matches no step >= 1): replay-safe.
__global__ void zero_tags(u32x4* __restrict__ hb) {
    u32x4 z = {0u, 0u, 0u, 0u};
    hb[blockIdx.x * 256 + threadIdx.x] = z;
}

__global__ __launch_bounds__(1024, 1) void lstm_persist(
    const unsigned short* __restrict__ wpack,
    const float* __restrict__ input_seq,
    const float* __restrict__ bias,
    unsigned int* __restrict__ hbuf,     // [2][BATCH][HSZ] tagged u32
    float* __restrict__ hlast)
{
    __shared__ __align__(16) unsigned short lds_B[16][584];   // [batch][k] +8 pad
    __shared__ __align__(16) unsigned short lds_hn[16][256];  // own-half h staging
    const int tid = threadIdx.x;
    const int bid = blockIdx.x;     // 32 WGs
    const int gi  = bid >> 1;       // batch-group 0..15
    const int p   = bid & 1;        // half: gate-slices jj in [8p, 8p+8)

    const int w  = tid >> 6;        // wave 0..15
    const int l  = tid & 63;
    const int bb = l & 15;          // batch within group (D col)
    const int lg = l >> 4;
    const int jj = p * 8 + (w >> 1);
    const int mbase = (w & 1) * 4;  // 4 M-tiles per wave

    // ---- one-time: W slice into registers (288 VGPRs) ----
    short8 wf[4][NKT];
#pragma unroll
    for (int mi = 0; mi < 4; ++mi)
#pragma unroll
        for (int kt = 0; kt < NKT; ++kt)
            wf[mi][kt] = *reinterpret_cast<const short8*>(
                wpack + (((size_t)(jj * 8 + mbase + mi) * NKT + kt) * 64 + l) * 8);

    int ghc[4];
    float bs[4][4];
#pragma unroll
    for (int mi = 0; mi < 4; ++mi) {
        ghc[mi] = jj * 32 + 4 * (mbase + mi) + lg;   // global h col (own half)
#pragma unroll
        for (int q = 0; q < 4; ++q) bs[mi][q] = bias[q * HSZ + ghc[mi]];
    }
    float cc[4] = {0.f, 0.f, 0.f, 0.f};

    // zero lds_B h region (h(0)=0); stage x(0); prefetch x(1)
    {
        const int zb = tid >> 6, zc = (tid & 63) * 8;
        u32x4 z = {0u, 0u, 0u, 0u};
        *reinterpret_cast<u32x4*>(&lds_B[zb][zc]) = z;
    }
    const int sb = tid & 15, sc = (tid >> 4) & 31;
    const float* xbase = input_seq + (size_t)(gi * BG + sb) * (TSTEPS * ISZ) + sc * 2;
    float2 xr = {0.f, 0.f};
    if (tid < 512) {
        xr = *reinterpret_cast<const float2*>(xbase);
        unsigned px = (unsigned)f2bf(xr.x) | ((unsigned)f2bf(xr.y) << 16);
        *reinterpret_cast<unsigned*>(&lds_B[sb][HSZ + sc * 2]) = px;
        xr = *reinterpret_cast<const float2*>(xbase + ISZ);   // x(1)
    }

    u64t* const tb0 = reinterpret_cast<u64t*>(hbuf);
    u64t* const tb1 = reinterpret_cast<u64t*>(hbuf + (size_t)BATCH * HSZ);
    const int b_ = tid >> 6, pr = tid & 63;     // publish/poll mapping
    const size_t myrow  = (size_t)(gi * BG + b_) * 256;       // u64s per batch row
    const size_t pubIdx = myrow + (size_t)p * 128 + pr * 2;
    const size_t polIdx = myrow + (size_t)(1 - p) * 128 + pr * 2;
    const int rcol = (1 - p) * 256 + pr * 4;    // LDS col base of remote chunk
    __syncthreads();

    for (int s = 0; s < TSTEPS; ++s) {
        // ---- acquire peer half of h(s): tagged poll (poll IS the load) ----
        if (s > 0) {
            u64t* tb = (s & 1) ? tb1 : tb0;
            const u64t want = ((u64t)s << 48) | ((u64t)s << 16);
            u64t v0 = ld_tag(tb + polIdx);
            u64t v1 = ld_tag(tb + polIdx + 1);
            while ((v0 & 0xFFFF0000FFFF0000ull) != want) v0 = ld_tag(tb + polIdx);
            while ((v1 & 0xFFFF0000FFFF0000ull) != want) v1 = ld_tag(tb + polIdx + 1);
            const unsigned d0 = (unsigned)(v0 & 0xFFFFu) | ((unsigned)(v0 >> 32) << 16);
            const unsigned d1 = (unsigned)(v1 & 0xFFFFu) | ((unsigned)(v1 >> 32) << 16);
            *reinterpret_cast<uint2*>(&lds_B[b_][rcol]) = make_uint2(d0, d1);
        }
        __syncthreads();   // A: full B = [h(s); x(s)] staged

        f32x4 acc[4];
#pragma unroll
        for (int mi = 0; mi < 4; ++mi) acc[mi] = (f32x4){0.f, 0.f, 0.f, 0.f};
#pragma unroll
        for (int kt = 0; kt < NKT; ++kt) {
            const short8 bf = *reinterpret_cast<const short8*>(
                &lds_B[bb][kt * 32 + lg * 8]);
#pragma unroll
            for (int mi = 0; mi < 4; ++mi)
                acc[mi] = __builtin_amdgcn_mfma_f32_16x16x32_bf16(
                    wf[mi][kt], bf, acc[mi], 0, 0, 0);
        }
        __syncthreads();   // B: all lds_B reads done

        if (s == TSTEPS - 1) {
#pragma unroll
            for (int mi = 0; mi < 4; ++mi) {
                const float fg = sig_(acc[mi][0] + bs[mi][0]);
                const float ig = sig_(acc[mi][1] + bs[mi][1]);
                const float cp = tanh_(acc[mi][2] + bs[mi][2]);
                const float og = sig_(acc[mi][3] + bs[mi][3]);
                cc[mi] = fg * cc[mi] + ig * cp;
                hlast[(size_t)(gi * BG + bb) * HSZ + ghc[mi]] = og * tanh_(cc[mi]);
            }
            break;
        }
        // ---- cell update: own h half -> lds_B (next step) + lds_hn (publish) ----
#pragma unroll
        for (int mi = 0; mi < 4; ++mi) {
            const float fg = sig_(acc[mi][0] + bs[mi][0]);
            const float ig = sig_(acc[mi][1] + bs[mi][1]);
            const float cp = tanh_(acc[mi][2] + bs[mi][2]);
            const float og = sig_(acc[mi][3] + bs[mi][3]);
            cc[mi] = fg * cc[mi] + ig * cp;
            const unsigned short hb16 = f2bf(og * tanh_(cc[mi]));
            lds_B[bb][ghc[mi]] = hb16;
            lds_hn[bb][ghc[mi] - p * 256] = hb16;
        }
        // stage x(s+1); prefetch x(s+2)
        if (tid < 512) {
            unsigned px = (unsigned)f2bf(xr.x) | ((unsigned)f2bf(xr.y) << 16);
            *reinterpret_cast<unsigned*>(&lds_B[sb][HSZ + sc * 2]) = px;
            if (s + 2 < TSTEPS)
                xr = *reinterpret_cast<const float2*>(xbase + (size_t)(s + 2) * ISZ);
        }
        __syncthreads();   // C: lds_hn complete

        // ---- publish own half of h(s+1): coalesced tagged u64 stores ----
        {
            u64t* tb = ((s + 1) & 1) ? tb1 : tb0;
            const u64t hv = *reinterpret_cast<const u64t*>(&lds_hn[b_][pr * 4]);
            const u64t tag = (u64t)(unsigned)(s + 1);
            const u64t TT = (tag << 16) | (tag << 48);
            const u64t w0 = (hv & 0xFFFFull) | (((hv >> 16) & 0xFFFFull) << 32) | TT;
            const u64t w1 = ((hv >> 32) & 0xFFFFull) | (((hv >> 48) & 0xFFFFull) << 32) | TT;
            st_tag(tb + pubIdx, w0);
            st_tag(tb + pubIdx + 1, w1);
        }
    }
}

// out[b] = h_last[b,:] . Wout + bout
__global__ void out_kernel(const float* __restrict__ hlast,
                           const float* __restrict__ wout,
                           const float* __restrict__ bout,
                           float* __restrict__ out)
{
    const int b = blockIdx.x;
    const int l = threadIdx.x;
    float p = 0.f;
    for (int k = l; k < HSZ; k += 64)
        p += hlast[(size_t)b * HSZ + k] * wout[k];
    for (int off = 32; off > 0; off >>= 1)
        p += __shfl_down(p, off, 64);
    if (l == 0) out[b] = p + bout[0];
}

extern "C" void kernel_launch(void* const* d_in, const int* in_sizes, int n_in,
                              void* d_out, int out_size, void* d_ws, size_t ws_size,
                              hipStream_t stream) {
    const float* input_seq = (const float*)d_in[0];
    const float* Kin       = (const float*)d_in[1];
    const float* R         = (const float*)d_in[2];
    const float* bias      = (const float*)d_in[3];
    const float* Wout      = (const float*)d_in[4];
    const float* bout      = (const float*)d_in[5];
    float* out = (float*)d_out;

    char* ws = (char*)d_ws;
    unsigned short* wpack = (unsigned short*)(ws);                    // 2,359,296 B
    unsigned int* hbuf    = (unsigned int*)(ws + 2359296);            // 1,048,576 B
    float* hlast          = (float*)(ws + 2359296 + 1048576);         //   524,288 B

    zero_tags<<<dim3(256), dim3(256), 0, stream>>>((u32x4*)hbuf);
    pack_w<<<dim3(576), dim3(256), 0, stream>>>(R, Kin, wpack);
    lstm_persist<<<dim3(32), dim3(1024), 0, stream>>>(
        wpack, input_seq, bias, hbuf, hlast);
    out_kernel<<<dim3(256), dim3(64), 0, stream>>>(hlast, Wout, bout, out);
}

// Round 7
// 2027.640 us; speedup vs baseline: 7.3859x; 7.3859x over previous
//
#include <hip/hip_runtime.h>

// LSTM: B=256, T=512, I=64, H=512, G=4H=2048.
// gates = W @ [h; x], W = [R | kernel^T], K = 576.
// Persistent kernel: 128 WGs x 512 threads = 16 batch-groups x 8 WGs.
// W pinned in AGPRs (144/lane via "+a" pin; MFMA reads A from AGPR on gfx950),
// c in VGPRs. h exchange: TAGGED u64s ((s<<16)|bf16 pairs), relaxed agent-scope
// atomics, double-buffered by parity. Poll IS the data load.
#define TSTEPS 512
#define BATCH  256
#define ISZ    64
#define HSZ    512
#define GSZ    2048
#define NKT    18
#define BG     16

typedef __attribute__((ext_vector_type(8))) short short8;
typedef __attribute__((ext_vector_type(4))) float f32x4;
typedef __attribute__((ext_vector_type(4))) unsigned int u32x4;
typedef unsigned long long u64t;

static __device__ __forceinline__ unsigned short f2bf(float f) {
    unsigned int u = __float_as_uint(f);
    return (unsigned short)((u + 0x7fffu + ((u >> 16) & 1u)) >> 16);  // RNE
}
static __device__ __forceinline__ float sig_(float x) {
    return 1.0f / (1.0f + __expf(-x));
}
static __device__ __forceinline__ float tanh_(float x) {
    float e = __expf(-2.0f * fabsf(x));
    float t = (1.0f - e) / (1.0f + e);
    return copysignf(t, x);
}

// Pack W = [R | kernel^T] (fp32) into bf16 MFMA A-fragment order.
// Frag t = ((jj*8 + m)*18 + kt)*64 + lane; row r = 16m + (lane&15);
// gate q = r&3; hco = r>>2; global row = q*512 + jj*32 + hco.
__global__ void pack_w(const float* __restrict__ R, const float* __restrict__ Kin,
                       unsigned short* __restrict__ wpack)
{
    const int t  = blockIdx.x * 256 + threadIdx.x;
    const int l  = t & 63;
    const int kt = (t >> 6) % NKT;
    const int m  = (t / (64 * NKT)) & 7;
    const int jj = t / (64 * NKT * 8);
    const int r   = 16 * m + (l & 15);
    const int q   = r & 3;
    const int hco = r >> 2;
    const int grow  = q * HSZ + jj * 32 + hco;
    const int kbase = kt * 32 + (l >> 4) * 8;
    unsigned int pk[4];
#pragma unroll
    for (int p = 0; p < 4; ++p) {
        const int k0 = kbase + 2 * p;
        const int k1 = k0 + 1;
        const float f0 = (k0 < HSZ) ? R[(size_t)grow * HSZ + k0]
                                    : Kin[(size_t)(k0 - HSZ) * GSZ + grow];
        const float f1 = (k1 < HSZ) ? R[(size_t)grow * HSZ + k1]
                                    : Kin[(size_t)(k1 - HSZ) * GSZ + grow];
        pk[p] = (unsigned)f2bf(f0) | ((unsigned)f2bf(f1) << 16);
    }
    uint4 v = make_uint4(pk[0], pk[1], pk[2], pk[3]);
    *reinterpret_cast<uint4*>(wpack + (size_t)t * 8) = v;
}

// Zero tagged h buffer each launch (tag 0 matches no step >= 1): replay-safe.
__global__ void zero_tags(u32x4* __restrict__ hb) {
    u32x4 z = {0u, 0u, 0u, 0u};
    hb[blockIdx.x * 256 + threadIdx.x] = z;
}

__global__ __launch_bounds__(512, 1) void lstm_persist(
    const unsigned short* __restrict__ wpack,
    const float* __restrict__ input_seq,
    const float* __restrict__ bias,
    unsigned int* __restrict__ hbuf,     // [2][BATCH][HSZ] tagged dwords
    float* __restrict__ hlast)
{
    __shared__ __align__(16) unsigned short lds_B[16][584];   // [batch][k]
    __shared__ __align__(16) unsigned short lds_hn[16][68];   // new-h staging
    const int tid = threadIdx.x;
    const int bid = blockIdx.x;
    const int gi = (bid & 7) + 8 * (bid >> 6);   // batch-group
    const int jw = (bid >> 3) & 7;               // h-col window [jw*64, +64)

    const int w  = tid >> 6;
    const int l  = tid & 63;
    const int bb = l & 15;
    const int lg = l >> 4;
    const int jj = 2 * jw + (w >> 2);
    const int mw = w & 3;
    const int m0 = 2 * mw, m1 = 2 * mw + 1;

    // ---- one-time: W fragments -> registers, PINNED into AGPRs ----
    short8 wA[NKT], wB[NKT];
#pragma unroll
    for (int kt = 0; kt < NKT; ++kt) {
        wA[kt] = *reinterpret_cast<const short8*>(
            wpack + (((size_t)(jj * 8 + m0) * NKT + kt) * 64 + l) * 8);
        wB[kt] = *reinterpret_cast<const short8*>(
            wpack + (((size_t)(jj * 8 + m1) * NKT + kt) * 64 + l) * 8);
    }
#pragma unroll
    for (int kt = 0; kt < NKT; ++kt) {
        asm volatile("" : "+a"(wA[kt]));   // pin: value lives in 4 AGPRs
        asm volatile("" : "+a"(wB[kt]));
    }
    const int hc0 = 4 * m0 + lg, hc1 = 4 * m1 + lg;
    const int gh0 = jj * 32 + hc0, gh1 = jj * 32 + hc1;
    float bs0[4], bs1[4];
#pragma unroll
    for (int qg = 0; qg < 4; ++qg) {
        bs0[qg] = bias[qg * HSZ + gh0];
        bs1[qg] = bias[qg * HSZ + gh1];
    }

    float c0 = 0.f, c1 = 0.f;

    // consumer mapping: thread (sb, sc) stages batch sb, cols [sc*16, +16)
    const int sb = tid & 15, sc = tid >> 4;
    const float* xbase = input_seq + (size_t)(gi * BG + sb) * (TSTEPS * ISZ) + sc * 2;
    float2 xr = *reinterpret_cast<const float2*>(xbase);

    u64t* const hb0 = reinterpret_cast<u64t*>(hbuf);
    u64t* const hb1 = reinterpret_cast<u64t*>(hbuf + (size_t)BATCH * HSZ);
    const size_t csrc = ((size_t)(gi * BG + sb) * HSZ + sc * 16) >> 1;  // u64 idx
    // producer mapping: thread (b_, pr) stores batch b_, cols jw*64+pr*2 (+1)
    const int b_ = tid >> 5, pr = tid & 31;
    const size_t pdst = ((size_t)(gi * BG + b_) * HSZ + jw * 64 + pr * 2) >> 1;

    for (int s = 0; s < TSTEPS; ++s) {
        // stage x(s) first (independent of the poll); prefetch x(s+1)
        {
            unsigned px = (unsigned)f2bf(xr.x) | ((unsigned)f2bf(xr.y) << 16);
            *reinterpret_cast<unsigned*>(&lds_B[sb][HSZ + sc * 2]) = px;
            if (s + 1 < TSTEPS)
                xr = *reinterpret_cast<const float2*>(xbase + (size_t)(s + 1) * ISZ);
        }
        // ---- acquire h(s): poll tagged data (poll IS the load) ----
        if (s > 0) {
            const u64t* src = ((s & 1) ? hb1 : hb0) + csrc;
            const u64t want = ((u64t)s << 48) | ((u64t)s << 16);
            u64t v[8];
            bool ok;
            do {
                ok = true;
#pragma unroll
                for (int i = 0; i < 8; ++i)
                    v[i] = __hip_atomic_load(src + i, __ATOMIC_RELAXED,
                                             __HIP_MEMORY_SCOPE_AGENT);
#pragma unroll
                for (int i = 0; i < 8; ++i)
                    ok = ok && ((v[i] & 0xFFFF0000FFFF0000ull) == want);
            } while (!ok);
            unsigned d[8];
#pragma unroll
            for (int i = 0; i < 8; ++i)
                d[i] = (unsigned)(v[i] & 0xFFFFu) |
                       ((unsigned)(v[i] >> 16) & 0xFFFF0000u);
            u32x4* dst = reinterpret_cast<u32x4*>(&lds_B[sb][sc * 16]);
            u32x4 lo = {d[0], d[1], d[2], d[3]};
            u32x4 hi = {d[4], d[5], d[6], d[7]};
            dst[0] = lo; dst[1] = hi;
        } else {
            u32x4 z = {0u, 0u, 0u, 0u};
            u32x4* dst = reinterpret_cast<u32x4*>(&lds_B[sb][sc * 16]);
            dst[0] = z; dst[1] = z;
        }
        __syncthreads();   // B: staging complete

        f32x4 acc0 = {0.f, 0.f, 0.f, 0.f};
        f32x4 acc1 = {0.f, 0.f, 0.f, 0.f};
#pragma unroll
        for (int kt = 0; kt < NKT; ++kt) {
            const short8 bf = *reinterpret_cast<const short8*>(
                &lds_B[bb][kt * 32 + lg * 8]);
            acc0 = __builtin_amdgcn_mfma_f32_16x16x32_bf16(wA[kt], bf, acc0, 0, 0, 0);
            acc1 = __builtin_amdgcn_mfma_f32_16x16x32_bf16(wB[kt], bf, acc1, 0, 0, 0);
        }

        // ---- lane-local cell update ----
        const float fg0 = sig_(acc0[0] + bs0[0]);
        const float ig0 = sig_(acc0[1] + bs0[1]);
        const float cp0 = tanh_(acc0[2] + bs0[2]);
        const float og0 = sig_(acc0[3] + bs0[3]);
        c0 = fg0 * c0 + ig0 * cp0;
        const float h0v = og0 * tanh_(c0);
        const float fg1 = sig_(acc1[0] + bs1[0]);
        const float ig1 = sig_(acc1[1] + bs1[1]);
        const float cp1 = tanh_(acc1[2] + bs1[2]);
        const float og1 = sig_(acc1[3] + bs1[3]);
        c1 = fg1 * c1 + ig1 * cp1;
        const float h1v = og1 * tanh_(c1);

        if (s == TSTEPS - 1) {
            hlast[(size_t)(gi * BG + bb) * HSZ + gh0] = h0v;
            hlast[(size_t)(gi * BG + bb) * HSZ + gh1] = h1v;
            break;
        }
        // stage new h into LDS (WG col window [jw*64, +64))
        const int cw = (w >> 2) * 32;
        lds_hn[bb][cw + hc0] = f2bf(h0v);
        lds_hn[bb][cw + hc1] = f2bf(h1v);
        __syncthreads();   // C: lds_hn ready; lds_B MFMA reads done

        // ---- publish h(s+1): coalesced tagged u64 atomic stores, no drain ----
        {
            const unsigned h2 = *reinterpret_cast<const unsigned*>(&lds_hn[b_][pr * 2]);
            const unsigned t16 = (unsigned)(s + 1) << 16;
            const unsigned lo = (h2 & 0xFFFFu) | t16;
            const unsigned hi = (h2 >> 16) | t16;
            const u64t tagged = ((u64t)hi << 32) | (u64t)lo;
            u64t* dst = (((s + 1) & 1) ? hb1 : hb0) + pdst;
            __hip_atomic_store(dst, tagged, __ATOMIC_RELAXED,
                               __HIP_MEMORY_SCOPE_AGENT);
        }
    }
}

// out[b] = h_last[b,:] . Wout + bout
__global__ void out_kernel(const float* __restrict__ hlast,
                           const float* __restrict__ wout,
                           const float* __restrict__ bout,
                           float* __restrict__ out)
{
    const int b = blockIdx.x;
    const int l = threadIdx.x;
    float p = 0.f;
    for (int k = l; k < HSZ; k += 64)
        p += hlast[(size_t)b * HSZ + k] * wout[k];
    for (int off = 32; off > 0; off >>= 1)
        p += __shfl_down(p, off, 64);
    if (l == 0) out[b] = p + bout[0];
}

extern "C" void kernel_launch(void* const* d_in, const int* in_sizes, int n_in,
                              void* d_out, int out_size, void* d_ws, size_t ws_size,
                              hipStream_t stream) {
    const float* input_seq = (const float*)d_in[0];
    const float* Kin       = (const float*)d_in[1];
    const float* R         = (const float*)d_in[2];
    const float* bias      = (const float*)d_in[3];
    const float* Wout      = (const float*)d_in[4];
    const float* bout      = (const float*)d_in[5];
    float* out = (float*)d_out;

    char* ws = (char*)d_ws;
    unsigned short* wpack = (unsigned short*)(ws);                    // 2,359,296 B
    unsigned int* hbuf    = (unsigned int*)(ws + 2359296);            // 1,048,576 B
    float* hlast          = (float*)(ws + 2359296 + 1048576);         //   524,288 B

    zero_tags<<<dim3(256), dim3(256), 0, stream>>>((u32x4*)hbuf);
    pack_w<<<dim3(576), dim3(256), 0, stream>>>(R, Kin, wpack);
    lstm_persist<<<dim3(128), dim3(512), 0, stream>>>(
        wpack, input_seq, bias, hbuf, hlast);
    out_kernel<<<dim3(256), dim3(64), 0, stream>>>(hlast, Wout, bout, out);
}